// Round 9
// baseline (115.374 us; speedup 1.0000x reference)
//
#include <hip/hip_runtime.h>

#define BATCH_N 65536
#define SEQ_N   128

// Native clang vector type — accepted by __builtin_nontemporal_load/store.
typedef float v2f __attribute__((ext_vector_type(2)));

// One thread per batch element; 128-step sequential recurrence in registers.
// 65536 threads = 1024 waves = exactly 1 wave per SIMD chip-wide: no TLP, so
// ALL latency hiding must come from ILP inside the one wave (R6's 2-wave
// producer/consumer split regressed: LDS+barrier overhead > TLP gain).
// Three independent streams fused at ROW granularity (R5 structure):
//   per row i of a 16-row phase:
//     - 1 global load of chunk k+2 row i      (memory stream)
//     - preRow of chunk k+1 row i             (d-chain: ~11 VALU + 1 trans)
//     - stepRow of chunk k row i              (s-chain: ~19 VALU + 4 trans + store)
// R8 isolation test: TEMPORAL stores (plain) instead of nontemporal. NT
// stores bypass L2/L3 and commit at HBM speed inside the kernel's critical
// window — with 1 wave/SIMD any write-queue backpressure stalls the wave
// with nothing to cover it. Temporal stores land in L2 (~1 MB/XCD per phase,
// fits 4 MB) and drain asynchronously behind the wave. Counter-risk: L2/L3
// write allocation may evict input L3 residency (FETCH 33 -> up to 64 MB).
// Trans budget (from R7): failure multiplier w11*d^-w12 carried in LOG
// domain (md = fma(-w12, log2 d, log2 w11)) and folded into the step's exp2
// exponents; success/failure flag rides in sign(D) (d in [1,10] > 0):
//   D = success ? +d_new : -d_new;  E = success ? (11-d_old)*hb : md.
// Step math:  success P = (exp2(aa+x) - exp2(aa)) * E * s
//             failure P = exp2(aa+x+md) - exp2(x+md)        (mult = 1)
// with aa = success ? w8l - w9*log2 s : w13*log2(s+1), x = omr*(w10l|w14l).
__global__ __launch_bounds__(256, 1) void fsrs_kernel(
    const v2f* __restrict__ in,   // (SEQ, BATCH) of (t, rating)
    const float* __restrict__ w,  // 17 weights
    v2f*       __restrict__ out)  // (SEQ, BATCH) of (s, d) then (BATCH) final
{
    const int b = blockIdx.x * 256 + threadIdx.x;

    const float w0 = w[0], w1 = w[1], w2 = w[2], w3 = w[3];
    const float w4 = w[4], w5 = w[5], w6 = w[6], w7 = w[7];
    const float w9 = w[9], w12 = w[12], w13 = w[13];
    const float w15 = w[15], w16 = w[16];
    constexpr float LOG2E = 1.44269504088896340736f;
    const float w8l  = w[8]  * LOG2E;   // exp(w8)*s^-w9 = exp2(w8l - w9*log2 s)
    const float w10l = w[10] * LOG2E;
    const float w14l = w[14] * LOG2E;
    const float lw11 = __builtin_amdgcn_logf(w[11]);   // log2(w11), one-time
    const float omw7   = 1.0f - w7;
    const float omw7w6 = omw7 * w6;
    const float dc0    = w7 * w4 + 3.0f * omw7w6;

    const v2f* ip = in  + b;
    v2f*       op = out + b;

    float s = 0.01f;       // stability state (serial s-chain)
    float dpre = 1.0f;     // d running ahead (serial d-chain, 1 chunk early)

    v2f rawA[16], rawB[16];
    float tX[16], dX[16], eX[16];   // t, signed new-d, success-mult | log-mult
    float tY[16], dY[16], eY[16];

    // Prologue-only burst load of a 16-row chunk.
    auto loadC = [&](v2f* raw, int base) {
#pragma unroll
        for (int i = 0; i < 16; ++i) raw[i] = ip[(base + i) * BATCH_N];
    };

    // d-chain row: uses/updates dpre (old d on entry). Writes:
    //   E = success ? (11-d_old)*hb : log2(w11*d_old^-w12)
    //   D = success ? +d_new : -d_new      (flag in sign; |D| = output d)
    auto preRow = [&](v2f r, float* T, float* D, float* E, int i) {
        const float tt = r.x, rating = r.y;
        const float hb = (rating == 2.0f) ? w15
                       : ((rating == 4.0f) ? w16 : 1.0f);
        const float eh = (11.0f - dpre) * hb;
        const float md = __builtin_fmaf(-w12,
                             __builtin_amdgcn_logf(dpre), lw11);
        const bool ok  = rating > 1.0f;
        E[i] = ok ? eh : md;
        const float nd = __builtin_fmaf(omw7, dpre,
                          __builtin_fmaf(-omw7w6, rating, dc0));
        dpre = fminf(fmaxf(nd, 1.0f), 10.0f);
        T[i] = tt;
        D[i] = ok ? dpre : -dpre;
    };

    // s-chain row + temporal store. Branch = sign(dd); md folded into
    // exponents on the failure path; failure clamp = med3(P, 0.01, s).
    auto stepRow = [&](float tt, float ee, float dd, int row) {
        const bool  sel = dd > 0.0f;                    // success?
        const float dc  = __builtin_fabsf(dd);
        const float q   = __builtin_fmaf(9.0f, s, tt);  // 9s + t
        const float omr = tt * __builtin_amdgcn_rcpf(q);// 1 - r
        const float x   = omr * (sel ? w10l : w14l);
        const float ls  = __builtin_amdgcn_logf(sel ? s : (s + 1.0f));
        const float aa  = sel ? __builtin_fmaf(-w9, ls, w8l) : (w13 * ls);
        const float g   = sel ? 0.0f : ee;              // exponent addend (md)
        const float xg  = x + g;
        const float u   = __builtin_amdgcn_exp2f(aa + xg);
        const float v   = __builtin_amdgcn_exp2f(sel ? aa : xg);
        const float mm  = sel ? (ee * s) : 1.0f;
        const float P   = (u - v) * mm;
        const float su  = fminf(s + P, 36500.0f);
        const float fl  = __builtin_amdgcn_fmed3f(P, 0.01f, s);
        s = sel ? su : fl;
        v2f o; o.x = s; o.y = dc;
        op[row * BATCH_N] = o;                          // temporal (L2-buffered)
    };

    // Prologue-only plain precompute of a chunk (no step material yet).
    auto preC = [&](const v2f* raw, float* T, float* D, float* E, int lo) {
#pragma unroll
        for (int i = 0; i < 16; ++i) {
            if (i < lo) continue;
            preRow(raw[i], T, D, E, i);
        }
    };

    // Fused phase: per row — load chunk lb row i into rawDst, preRow chunk
    // from rawSrc into (T2,D2,E2), step chunk sb row i from (T,D,E).
    auto fused = [&](const float* T, const float* D, const float* E,
                     int sb, int lo,
                     const v2f* rawSrc, float* T2, float* D2, float* E2,
                     bool doPre, v2f* rawDst, int lb, bool doLoad) {
#pragma unroll
        for (int i = 0; i < 16; ++i) {
            if (doLoad) rawDst[i] = ip[(lb + i) * BATCH_N];
            if (doPre)  preRow(rawSrc[i], T2, D2, E2, i);
            if (i >= lo) stepRow(T[i], E[i], D[i], sb + i);
        }
    };

    // ---- prologue: burst-load ch0, ch1; pre ch0; special row 0 ----
    loadC(rawA, 0);
    loadC(rawB, 16);

    const float r0 = rawA[0].y;
    {   // row 0: _first_step (d0 comes from rating only)
        const float d0 = fminf(fmaxf(
            __builtin_fmaf(-w5, r0 - 3.0f, w4), 1.0f), 10.0f);
        dpre = d0;
        tX[0] = rawA[0].x; dX[0] = d0; eX[0] = 1.0f;   // row 0 stepped specially
    }
    preC(rawA, tX, dX, eX, 1);     // ch0 -> X; rawA free

    {   // step row 0 (special): s0 from weight table
        const float wsel = (r0 < 2.5f) ? ((r0 < 1.5f) ? w0 : w1)
                                       : ((r0 < 3.5f) ? w2 : w3);
        const float ns = (r0 >= 1.0f && r0 <= 4.0f) ? wsel : 1.0f;
        s = fminf(fmaxf(ns, 0.01f), 36500.0f);
        v2f o; o.x = s; o.y = dX[0];
        op[0] = o;
    }

    // fused(0): step ch0 rows 1..15 | pre ch1 (rawB->Y) | load ch2 -> rawA
    fused(tX, dX, eX, 0, 1, rawB, tY, dY, eY, true, rawA, 32, true);

    // ---- main: c covers k=2c+1 (odd) and k=2c+2 (even) ----
    // fused(odd k):  step Y (ch k) | pre rawA (ch k+1) -> X | load ch k+2 -> rawB
    // fused(even k): step X (ch k) | pre rawB (ch k+1) -> Y | load ch k+2 -> rawA
#pragma unroll 1
    for (int c = 0; c < 3; ++c) {
        fused(tY, dY, eY, 16 * (2 * c + 1), 0,
              rawA, tX, dX, eX, true, rawB, 16 * (2 * c + 3), true);
        fused(tX, dX, eX, 16 * (2 * c + 2), 0,
              rawB, tY, dY, eY, true, rawA, 16 * (2 * c + 4), c < 2);
    }

    // ---- tail: fused(7): step ch7 (Y) only — no pre, no load ----
    fused(tY, dY, eY, 112, 0, rawA, tX, dX, eX, false, rawB, 0, false);

    // final_state, appended after the (SEQ, BATCH) outputs.
    {
        v2f o; o.x = s; o.y = __builtin_fabsf(dY[15]);
        op[SEQ_N * BATCH_N] = o;
    }
}

extern "C" void kernel_launch(void* const* d_in, const int* in_sizes, int n_in,
                              void* d_out, int out_size, void* d_ws, size_t ws_size,
                              hipStream_t stream) {
    const v2f*   in = (const v2f*)d_in[0];   // (128, 65536, 2) f32
    const float* w  = (const float*)d_in[1]; // (17,) f32
    v2f* out = (v2f*)d_out;                  // 128*65536 + 65536 float2
    fsrs_kernel<<<BATCH_N / 256, 256, 0, stream>>>(in, w, out);
}

// Round 10
// 114.456 us; speedup vs baseline: 1.0080x; 1.0080x over previous
//
#include <hip/hip_runtime.h>

#define BATCH_N 65536
#define SEQ_N   128

// Native clang vector type — accepted by __builtin_nontemporal_load/store.
typedef float v2f __attribute__((ext_vector_type(2)));

// One thread per batch element; 128-step sequential recurrence in registers.
// 65536 threads = 1024 waves = exactly 1 wave per SIMD chip-wide: no TLP, so
// ALL latency hiding must come from ILP inside the one wave. This version
// fuses the three independent instruction streams at ROW granularity:
//   per row i of a 16-row phase:
//     - 1 global load of chunk k+2 row i      (memory stream)
//     - preRow of chunk k+1 row i             (d-chain: ~10 VALU + 2 trans)
//     - stepRow of chunk k row i              (s-chain: ~18 VALU + 4 trans + NT store)
// The s-chain's serial dependency spine (~56 cy/row) is filled with the
// d-chain's and load stream's instructions and vice versa.
// Load->consume distance stays one full phase (~1900 cy >> ~900 cy HBM).
// NT stores are essential (R9 A/B): temporal stores occupy L2 in the
// kernel's critical window and regressed the kernel to 64 µs under rocprof.
// VGPR=80 is the exact intended fit: 16 in-flight v2f loads (32, row-wise
// pool reuse) + 48 cross-phase T/D/E — no spill (R9 counters).
// stepRow math: P = (exp2(aa+x) - exp2(sel?aa:x)) * m merges the success/
// failure algebra — success: A*e - A = A(e-1); failure: A*e - e = e(A-1).
__global__ __launch_bounds__(256, 1) void fsrs_kernel(
    const v2f* __restrict__ in,   // (SEQ, BATCH) of (t, rating)
    const float* __restrict__ w,  // 17 weights
    v2f*       __restrict__ out)  // (SEQ, BATCH) of (s, d) then (BATCH) final
{
    const int b = blockIdx.x * 256 + threadIdx.x;

    const float w0 = w[0], w1 = w[1], w2 = w[2], w3 = w[3];
    const float w4 = w[4], w5 = w[5], w6 = w[6], w7 = w[7];
    const float w9 = w[9], w11 = w[11], w12 = w[12], w13 = w[13];
    const float w15 = w[15], w16 = w[16];
    constexpr float LOG2E = 1.44269504088896340736f;
    const float w8l  = w[8]  * LOG2E;   // exp(w8)*s^-w9 = exp2(w8l - w9*log2 s)
    const float w10l = w[10] * LOG2E;
    const float w14l = w[14] * LOG2E;
    const float omw7   = 1.0f - w7;
    const float omw7w6 = omw7 * w6;
    const float dc0    = w7 * w4 + 3.0f * omw7w6;

    const v2f* ip = in  + b;
    v2f*       op = out + b;

    float s = 0.01f;       // stability state (serial s-chain)
    float dpre = 1.0f;     // d running ahead (serial d-chain, 1 chunk early)

    v2f rawA[16], rawB[16];
    float tX[16], dX[16], mX[16];   // t, new-d (output), merged multiplier
    float tY[16], dY[16], mY[16];

    // Prologue-only burst load of a 16-row chunk.
    auto loadC = [&](v2f* raw, int base) {
#pragma unroll
        for (int i = 0; i < 16; ++i) raw[i] = ip[(base + i) * BATCH_N];
    };

    // d-chain row: uses/updates dpre (old d on entry). M = success ?
    // (11-d_old)*hb : -(w11*d_old^-w12); sign(M) encodes the branch
    // ((11-d)>=1>0 and w11*d^-w12>0 always).
    auto preRow = [&](v2f r, float* T, float* D, float* M, int i) {
        const float tt = r.x, rating = r.y;
        const float hb = (rating == 2.0f) ? w15
                       : ((rating == 4.0f) ? w16 : 1.0f);
        const float eh = (11.0f - dpre) * hb;
        const float m2 = w11 * __builtin_amdgcn_exp2f(
                             -w12 * __builtin_amdgcn_logf(dpre));
        M[i] = (rating > 1.0f) ? eh : -m2;
        const float nd = __builtin_fmaf(omw7, dpre,
                          __builtin_fmaf(-omw7w6, rating, dc0));
        dpre = fminf(fmaxf(nd, 1.0f), 10.0f);
        T[i] = tt;
        D[i] = dpre;
    };

    // s-chain row + NT store. Branch known up front (sign of M): one log
    // serves s^-w9 (success) and (s+1)^w13 (failure); u-v merges the
    // (A,e) algebra; clamps split per-branch (success can't underflow
    // S_MIN; failure can't exceed s<=S_MAX).
    auto stepRow = [&](float tt, float ms, float dd, int row) {
        const bool  sel = ms > 0.0f;                    // success?
        const float q   = __builtin_fmaf(9.0f, s, tt);  // 9s + t
        const float omr = tt * __builtin_amdgcn_rcpf(q);// 1 - r
        const float x   = omr * (sel ? w10l : w14l);
        const float ls  = __builtin_amdgcn_logf(sel ? s : (s + 1.0f));
        const float aa  = sel ? __builtin_fmaf(-w9, ls, w8l) : (w13 * ls);
        const float u   = __builtin_amdgcn_exp2f(aa + x);   // A*e
        const float v   = __builtin_amdgcn_exp2f(sel ? aa : x); // A or e
        const float m   = sel ? (ms * s) : (-ms);
        const float P   = (u - v) * m;
        const float su  = fminf(s + P, 36500.0f);
        const float fl  = fmaxf(fminf(P, s), 0.01f);
        s = sel ? su : fl;
        v2f o; o.x = s; o.y = dd;
        __builtin_nontemporal_store(o, &op[row * BATCH_N]);
    };

    // Prologue-only plain precompute of a chunk (no step material yet).
    auto preC = [&](const v2f* raw, float* T, float* D, float* M, int lo) {
#pragma unroll
        for (int i = 0; i < 16; ++i) {
            if (i < lo) continue;
            preRow(raw[i], T, D, M, i);
        }
    };

    // Fused phase: per row — load chunk lb row i into rawDst, preRow chunk
    // from rawSrc into (T2,D2,M2), step chunk sb row i from (T,D,M).
    auto fused = [&](const float* T, const float* D, const float* M,
                     int sb, int lo,
                     const v2f* rawSrc, float* T2, float* D2, float* M2,
                     bool doPre, v2f* rawDst, int lb, bool doLoad) {
#pragma unroll
        for (int i = 0; i < 16; ++i) {
            if (doLoad) rawDst[i] = ip[(lb + i) * BATCH_N];
            if (doPre)  preRow(rawSrc[i], T2, D2, M2, i);
            if (i >= lo) stepRow(T[i], M[i], D[i], sb + i);
        }
    };

    // ---- prologue: burst-load ch0, ch1; pre ch0; special row 0 ----
    loadC(rawA, 0);
    loadC(rawB, 16);

    const float r0 = rawA[0].y;
    {   // row 0: _first_step (d0 comes from rating only)
        const float d0 = fminf(fmaxf(
            __builtin_fmaf(-w5, r0 - 3.0f, w4), 1.0f), 10.0f);
        dpre = d0;
        tX[0] = rawA[0].x; dX[0] = d0; mX[0] = 1.0f;
    }
    preC(rawA, tX, dX, mX, 1);     // ch0 -> X; rawA free

    {   // step row 0 (special): s0 from weight table
        const float wsel = (r0 < 2.5f) ? ((r0 < 1.5f) ? w0 : w1)
                                       : ((r0 < 3.5f) ? w2 : w3);
        const float ns = (r0 >= 1.0f && r0 <= 4.0f) ? wsel : 1.0f;
        s = fminf(fmaxf(ns, 0.01f), 36500.0f);
        v2f o; o.x = s; o.y = dX[0];
        __builtin_nontemporal_store(o, &op[0]);
    }

    // fused(0): step ch0 rows 1..15 | pre ch1 (rawB->Y) | load ch2 -> rawA
    fused(tX, dX, mX, 0, 1, rawB, tY, dY, mY, true, rawA, 32, true);

    // ---- main: c covers k=2c+1 (odd) and k=2c+2 (even) ----
    // fused(odd k):  step Y (ch k) | pre rawA (ch k+1) -> X | load ch k+2 -> rawB
    // fused(even k): step X (ch k) | pre rawB (ch k+1) -> Y | load ch k+2 -> rawA
#pragma unroll 1
    for (int c = 0; c < 3; ++c) {
        fused(tY, dY, mY, 16 * (2 * c + 1), 0,
              rawA, tX, dX, mX, true, rawB, 16 * (2 * c + 3), true);
        fused(tX, dX, mX, 16 * (2 * c + 2), 0,
              rawB, tY, dY, mY, true, rawA, 16 * (2 * c + 4), c < 2);
    }

    // ---- tail: fused(7): step ch7 (Y) only — no pre, no load ----
    fused(tY, dY, mY, 112, 0, rawA, tX, dX, mX, false, rawB, 0, false);

    // final_state, appended after the (SEQ, BATCH) outputs.
    {
        v2f o; o.x = s; o.y = dY[15];
        op[SEQ_N * BATCH_N] = o;
    }
}

extern "C" void kernel_launch(void* const* d_in, const int* in_sizes, int n_in,
                              void* d_out, int out_size, void* d_ws, size_t ws_size,
                              hipStream_t stream) {
    const v2f*   in = (const v2f*)d_in[0];   // (128, 65536, 2) f32
    const float* w  = (const float*)d_in[1]; // (17,) f32
    v2f* out = (v2f*)d_out;                  // 128*65536 + 65536 float2
    fsrs_kernel<<<BATCH_N / 256, 256, 0, stream>>>(in, w, out);
}